// Round 2
// baseline (1343.389 us; speedup 1.0000x reference)
//
#include <hip/hip_runtime.h>
#include <cstdint>
#include <cstddef>

#define H_DIM 2560
#define I_DIM 6912
#define NTOK  8192   // B*S = 4*2048

typedef __attribute__((ext_vector_type(8))) __bf16 bf16x8;
typedef __attribute__((ext_vector_type(4))) float  f32x4;

// ---- async global->LDS, 16B per lane -------------------------------------
__device__ inline void gld16(void* lds, const void* g) {
    __builtin_amdgcn_global_load_lds(
        (__attribute__((address_space(1))) void*)(void*)g,
        (__attribute__((address_space(3))) void*)lds, 16, 0, 0);
}

// ---- prep: f32 -> bf16 (8 elems/thread) ----------------------------------
__global__ __launch_bounds__(256) void cvt_x_kernel(const float* __restrict__ x,
                                                    __bf16* __restrict__ xb, int n8) {
    int gid = blockIdx.x * 256 + threadIdx.x;
    if (gid >= n8) return;
    const float4* p = (const float4*)(x + (size_t)gid * 8);
    float4 v0 = p[0], v1 = p[1];
    bf16x8 o;
    o[0] = (__bf16)v0.x; o[1] = (__bf16)v0.y; o[2] = (__bf16)v0.z; o[3] = (__bf16)v0.w;
    o[4] = (__bf16)v1.x; o[5] = (__bf16)v1.y; o[6] = (__bf16)v1.z; o[7] = (__bf16)v1.w;
    *(bf16x8*)(xb + (size_t)gid * 8) = o;
}

// ---- prep: unpack SIMD-interleaved 2-bit ternary -> bf16 ------------------
// NOTE: harness materializes integer inputs as int32 on device (one packed
// byte value 0..255 per int32 element).
// weight (row i, col k): blk=k/128, grp=(k%128)/32, j=k%32,
// byte = packed[i*(K/4) + blk*32 + j], w = ((byte >> (6-2*grp)) & 3) - 1
__global__ __launch_bounds__(256) void unpack_w_kernel(const int* __restrict__ packed,
                                                       __bf16* __restrict__ out,
                                                       int M, int K,
                                                       const float* __restrict__ norm) {
    int gid = blockIdx.x * 256 + threadIdx.x;
    int per_row = K >> 3;
    if (gid >= M * per_row) return;
    int i  = gid / per_row;
    int k0 = (gid % per_row) * 8;
    int blk = k0 >> 7;
    int grp = (k0 >> 5) & 3;
    int j0  = k0 & 31;
    int shift = 6 - 2 * grp;
    const int* p = packed + (size_t)i * (K >> 2) + blk * 32 + j0;
    int4 v0 = *(const int4*)p;
    int4 v1 = *(const int4*)(p + 4);
    int vals[8] = {v0.x, v0.y, v0.z, v0.w, v1.x, v1.y, v1.z, v1.w};
    bf16x8 o;
#pragma unroll
    for (int b = 0; b < 8; ++b) {
        float f = (float)(((vals[b] >> shift) & 3) - 1);
        if (norm) f *= norm[k0 + b];
        o[b] = (__bf16)f;
    }
    *(bf16x8*)(out + (size_t)i * K + k0) = o;
}

// ---- fused gate+up GEMM + ReLU^2 gating -----------------------------------
// C tile 128(M tokens) x 64(N = I cols), BK=64, 4 waves as 2x2, wave = 64x32.
__global__ __launch_bounds__(256) void gemm_gateup(const __bf16* __restrict__ xb,   // [NTOK][H]
                                                   const __bf16* __restrict__ wg,   // [I][H]
                                                   const __bf16* __restrict__ wu,   // [I][H]
                                                   const float* __restrict__ gs_p,
                                                   const float* __restrict__ us_p,
                                                   __bf16* __restrict__ hidden) {   // [NTOK][I]
    __shared__ __bf16 sA[128 * 64];
    __shared__ __bf16 sG[64 * 64];
    __shared__ __bf16 sU[64 * 64];

    const int m0 = blockIdx.x * 128;
    const int n0 = blockIdx.y * 64;
    const int t    = threadIdx.x;
    const int lane = t & 63;
    const int wid  = t >> 6;
    const int wm = wid >> 1, wn = wid & 1;

    // staging coords: 256 threads x 16B = 32 rows of 64 bf16 per issue
    const int rA = t >> 3;
    const int c8 = (t & 7) * 8;
    const __bf16* gA = xb + (size_t)(m0 + rA) * H_DIM + c8;
    const __bf16* gG = wg + (size_t)(n0 + rA) * H_DIM + c8;
    const __bf16* gU = wu + (size_t)(n0 + rA) * H_DIM + c8;
    __bf16* lA = sA + (size_t)t * 8;
    __bf16* lG = sG + (size_t)t * 8;
    __bf16* lU = sU + (size_t)t * 8;

    f32x4 accg[4][2], accu[4][2];
#pragma unroll
    for (int a = 0; a < 4; ++a)
#pragma unroll
        for (int b = 0; b < 2; ++b) { accg[a][b] = (f32x4){0,0,0,0}; accu[a][b] = (f32x4){0,0,0,0}; }

    const int l15 = lane & 15;
    const int ksub = (lane >> 4) * 8;
    const int rowa0 = wm * 64 + l15;
    const int rowb0 = wn * 32 + l15;

    for (int k0 = 0; k0 < H_DIM; k0 += 64) {
#pragma unroll
        for (int it = 0; it < 4; ++it)
            gld16(lA + it * 2048, gA + (size_t)it * 32 * H_DIM + k0);
#pragma unroll
        for (int it = 0; it < 2; ++it) {
            gld16(lG + it * 2048, gG + (size_t)it * 32 * H_DIM + k0);
            gld16(lU + it * 2048, gU + (size_t)it * 32 * H_DIM + k0);
        }
        __syncthreads();
#pragma unroll
        for (int kk = 0; kk < 2; ++kk) {
            bf16x8 a[4], bg[2], bu[2];
#pragma unroll
            for (int fm = 0; fm < 4; ++fm)
                a[fm] = *(const bf16x8*)&sA[(rowa0 + fm * 16) * 64 + kk * 32 + ksub];
#pragma unroll
            for (int fn = 0; fn < 2; ++fn) {
                bg[fn] = *(const bf16x8*)&sG[(rowb0 + fn * 16) * 64 + kk * 32 + ksub];
                bu[fn] = *(const bf16x8*)&sU[(rowb0 + fn * 16) * 64 + kk * 32 + ksub];
            }
#pragma unroll
            for (int fm = 0; fm < 4; ++fm)
#pragma unroll
                for (int fn = 0; fn < 2; ++fn) {
                    accg[fm][fn] = __builtin_amdgcn_mfma_f32_16x16x32_bf16(a[fm], bg[fn], accg[fm][fn], 0, 0, 0);
                    accu[fm][fn] = __builtin_amdgcn_mfma_f32_16x16x32_bf16(a[fm], bu[fn], accu[fm][fn], 0, 0, 0);
                }
        }
        __syncthreads();
    }

    // epilogue: hidden = gs^2*us * relu(g)^2 * u  (gs > 0)
    const float gs = *gs_p, us = *us_p;
    const float comb = gs * gs * us;
    const int rowc0 = m0 + wm * 64 + (lane >> 4) * 4;
    const int colc0 = n0 + wn * 32 + l15;
#pragma unroll
    for (int fm = 0; fm < 4; ++fm)
#pragma unroll
        for (int fn = 0; fn < 2; ++fn)
#pragma unroll
            for (int j = 0; j < 4; ++j) {
                float g = accg[fm][fn][j];
                float u = accu[fm][fn][j];
                float r = fmaxf(g, 0.f);
                float h = comb * r * r * u;
                hidden[(size_t)(rowc0 + fm * 16 + j) * I_DIM + (colc0 + fn * 16)] = (__bf16)h;
            }
}

// ---- per-token rsqrt(mean(hidden^2)+eps) ----------------------------------
__global__ __launch_bounds__(256) void rms_rs_kernel(const __bf16* __restrict__ hidden,
                                                     float* __restrict__ rs) {
    const int tk = blockIdx.x;
    const __bf16* row = hidden + (size_t)tk * I_DIM;
    float s = 0.f;
    for (int idx = threadIdx.x; idx < I_DIM / 8; idx += 256) {
        bf16x8 v = *(const bf16x8*)&row[idx * 8];
#pragma unroll
        for (int j = 0; j < 8; ++j) { float f = (float)v[j]; s += f * f; }
    }
#pragma unroll
    for (int off = 32; off; off >>= 1) s += __shfl_down(s, off, 64);
    __shared__ float wsum[4];
    if ((threadIdx.x & 63) == 0) wsum[threadIdx.x >> 6] = s;
    __syncthreads();
    if (threadIdx.x == 0) {
        float tot = wsum[0] + wsum[1] + wsum[2] + wsum[3];
        rs[tk] = rsqrtf(tot / (float)I_DIM + 1e-6f);
    }
}

// ---- down GEMM: out[t,h] = ds * rs[t] * sum_i hidden[t,i]*Wd[h,i] ---------
// C tile 128(M tokens) x 128(N = H cols), BK=64, 4 waves as 2x2, wave = 64x64.
__global__ __launch_bounds__(256) void gemm_down(const __bf16* __restrict__ hidden, // [NTOK][I]
                                                 const __bf16* __restrict__ wd,     // [H][I] (norm_w folded)
                                                 const float* __restrict__ rs,
                                                 const float* __restrict__ ds_p,
                                                 float* __restrict__ out) {         // [NTOK][H]
    __shared__ __bf16 sA[128 * 64];
    __shared__ __bf16 sB[128 * 64];

    const int m0 = blockIdx.x * 128;
    const int n0 = blockIdx.y * 128;
    const int t    = threadIdx.x;
    const int lane = t & 63;
    const int wid  = t >> 6;
    const int wm = wid >> 1, wn = wid & 1;

    const int rA = t >> 3;
    const int c8 = (t & 7) * 8;
    const __bf16* gA = hidden + (size_t)(m0 + rA) * I_DIM + c8;
    const __bf16* gB = wd + (size_t)(n0 + rA) * I_DIM + c8;
    __bf16* lA = sA + (size_t)t * 8;
    __bf16* lB = sB + (size_t)t * 8;

    f32x4 acc[4][4];
#pragma unroll
    for (int a = 0; a < 4; ++a)
#pragma unroll
        for (int b = 0; b < 4; ++b) acc[a][b] = (f32x4){0,0,0,0};

    const int l15 = lane & 15;
    const int ksub = (lane >> 4) * 8;
    const int rowa0 = wm * 64 + l15;
    const int rowb0 = wn * 64 + l15;

    for (int k0 = 0; k0 < I_DIM; k0 += 64) {
#pragma unroll
        for (int it = 0; it < 4; ++it) {
            gld16(lA + it * 2048, gA + (size_t)it * 32 * I_DIM + k0);
            gld16(lB + it * 2048, gB + (size_t)it * 32 * I_DIM + k0);
        }
        __syncthreads();
#pragma unroll
        for (int kk = 0; kk < 2; ++kk) {
            bf16x8 a[4], b[4];
#pragma unroll
            for (int fm = 0; fm < 4; ++fm)
                a[fm] = *(const bf16x8*)&sA[(rowa0 + fm * 16) * 64 + kk * 32 + ksub];
#pragma unroll
            for (int fn = 0; fn < 4; ++fn)
                b[fn] = *(const bf16x8*)&sB[(rowb0 + fn * 16) * 64 + kk * 32 + ksub];
#pragma unroll
            for (int fm = 0; fm < 4; ++fm)
#pragma unroll
                for (int fn = 0; fn < 4; ++fn)
                    acc[fm][fn] = __builtin_amdgcn_mfma_f32_16x16x32_bf16(a[fm], b[fn], acc[fm][fn], 0, 0, 0);
        }
        __syncthreads();
    }

    const float ds = *ds_p;
    const int rowc0 = m0 + wm * 64 + (lane >> 4) * 4;
    const int colc0 = n0 + wn * 64 + l15;
#pragma unroll
    for (int fm = 0; fm < 4; ++fm)
#pragma unroll
        for (int j = 0; j < 4; ++j) {
            const int row = rowc0 + fm * 16 + j;
            const float sc = ds * rs[row];
#pragma unroll
            for (int fn = 0; fn < 4; ++fn)
                out[(size_t)row * H_DIM + (colc0 + fn * 16)] = sc * acc[fm][fn][j];
        }
}

// ---------------------------------------------------------------------------
extern "C" void kernel_launch(void* const* d_in, const int* in_sizes, int n_in,
                              void* d_out, int out_size, void* d_ws, size_t ws_size,
                              hipStream_t stream) {
    const float* x   = (const float*)d_in[0];
    const int*   gp  = (const int*)d_in[1];
    const float* gs  = (const float*)d_in[2];
    const int*   upk = (const int*)d_in[3];
    const float* us  = (const float*)d_in[4];
    const int*   dp  = (const int*)d_in[5];
    const float* dsc = (const float*)d_in[6];
    const float* nw  = (const float*)d_in[7];
    float* out = (float*)d_out;

    char* ws = (char*)d_ws;
    __bf16* xb     = (__bf16*)ws;  ws += (size_t)NTOK * H_DIM * 2;       // 41.9 MB
    __bf16* wgb    = (__bf16*)ws;  ws += (size_t)I_DIM * H_DIM * 2;      // 35.4 MB
    __bf16* wub    = (__bf16*)ws;  ws += (size_t)I_DIM * H_DIM * 2;      // 35.4 MB
    __bf16* wdb    = (__bf16*)ws;  ws += (size_t)H_DIM * I_DIM * 2;      // 35.4 MB
    __bf16* hidden = (__bf16*)ws;  ws += (size_t)NTOK * I_DIM * 2;       // 113.2 MB
    float*  rsbuf  = (float*)ws;   ws += (size_t)NTOK * 4;

    // prep
    cvt_x_kernel<<<(NTOK * H_DIM / 8 + 255) / 256, 256, 0, stream>>>(x, xb, NTOK * H_DIM / 8);
    unpack_w_kernel<<<(I_DIM * H_DIM / 8 + 255) / 256, 256, 0, stream>>>(gp, wgb, I_DIM, H_DIM, nullptr);
    unpack_w_kernel<<<(I_DIM * H_DIM / 8 + 255) / 256, 256, 0, stream>>>(upk, wub, I_DIM, H_DIM, nullptr);
    unpack_w_kernel<<<(H_DIM * I_DIM / 8 + 255) / 256, 256, 0, stream>>>(dp, wdb, H_DIM, I_DIM, nw);

    // gate+up fused GEMM + gating
    dim3 g1(NTOK / 128, I_DIM / 64);
    gemm_gateup<<<g1, 256, 0, stream>>>(xb, wgb, wub, gs, us, hidden);

    // RMSNorm scale
    rms_rs_kernel<<<NTOK, 256, 0, stream>>>(hidden, rsbuf);

    // down GEMM
    dim3 g3(NTOK / 128, H_DIM / 128);
    gemm_down<<<g3, 256, 0, stream>>>(hidden, wdb, rsbuf, dsc, out);
}

// Round 3
// 941.179 us; speedup vs baseline: 1.4273x; 1.4273x over previous
//
#include <hip/hip_runtime.h>
#include <cstdint>
#include <cstddef>

#define H_DIM 2560
#define I_DIM 6912
#define NTOK  8192   // B*S = 4*2048

typedef __attribute__((ext_vector_type(8))) __bf16 bf16x8;
typedef __attribute__((ext_vector_type(4))) float  f32x4;

// ---- async global->LDS, 16B per lane -------------------------------------
__device__ inline void gld16(void* lds, const void* g) {
    __builtin_amdgcn_global_load_lds(
        (__attribute__((address_space(1))) void*)(void*)g,
        (__attribute__((address_space(3))) void*)lds, 16, 0, 0);
}

// ---- prep: f32 -> bf16 (8 elems/thread) ----------------------------------
__global__ __launch_bounds__(256) void cvt_x_kernel(const float* __restrict__ x,
                                                    __bf16* __restrict__ xb, int n8) {
    int gid = blockIdx.x * 256 + threadIdx.x;
    if (gid >= n8) return;
    const float4* p = (const float4*)(x + (size_t)gid * 8);
    float4 v0 = p[0], v1 = p[1];
    bf16x8 o;
    o[0] = (__bf16)v0.x; o[1] = (__bf16)v0.y; o[2] = (__bf16)v0.z; o[3] = (__bf16)v0.w;
    o[4] = (__bf16)v1.x; o[5] = (__bf16)v1.y; o[6] = (__bf16)v1.z; o[7] = (__bf16)v1.w;
    *(bf16x8*)(xb + (size_t)gid * 8) = o;
}

// ---- prep: unpack SIMD-interleaved 2-bit ternary -> bf16 ------------------
// mode 0: dst row = i (direct, optional norm fold)
// mode 1: dst row = (i>>4)*32 + (i&15)        (gate rows of combined B')
// mode 2: dst row = (i>>4)*32 + 16 + (i&15)   (up rows of combined B')
__global__ __launch_bounds__(256) void unpack_w_kernel(const int* __restrict__ packed,
                                                       __bf16* __restrict__ out,
                                                       int M, int K,
                                                       const float* __restrict__ norm,
                                                       int mode) {
    int gid = blockIdx.x * 256 + threadIdx.x;
    int per_row = K >> 3;
    if (gid >= M * per_row) return;
    int i  = gid / per_row;
    int k0 = (gid % per_row) * 8;
    int blk = k0 >> 7;
    int grp = (k0 >> 5) & 3;
    int j0  = k0 & 31;
    int shift = 6 - 2 * grp;
    const int* p = packed + (size_t)i * (K >> 2) + blk * 32 + j0;
    int4 v0 = *(const int4*)p;
    int4 v1 = *(const int4*)(p + 4);
    int vals[8] = {v0.x, v0.y, v0.z, v0.w, v1.x, v1.y, v1.z, v1.w};
    bf16x8 o;
#pragma unroll
    for (int b = 0; b < 8; ++b) {
        float f = (float)(((vals[b] >> shift) & 3) - 1);
        if (norm) f *= norm[k0 + b];
        o[b] = (__bf16)f;
    }
    int dst = (mode == 0) ? i : ((i >> 4) * 32 + (i & 15) + ((mode == 2) ? 16 : 0));
    *(bf16x8*)(out + (size_t)dst * K + k0) = o;
}

// ---- per-token rsqrt(mean(hidden^2)+eps) ----------------------------------
__global__ __launch_bounds__(256) void rms_rs_kernel(const __bf16* __restrict__ hidden,
                                                     float* __restrict__ rs) {
    const int tk = blockIdx.x;
    const __bf16* row = hidden + (size_t)tk * I_DIM;
    float s = 0.f;
    for (int idx = threadIdx.x; idx < I_DIM / 8; idx += 256) {
        bf16x8 v = *(const bf16x8*)&row[idx * 8];
#pragma unroll
        for (int j = 0; j < 8; ++j) { float f = (float)v[j]; s += f * f; }
    }
#pragma unroll
    for (int off = 32; off; off >>= 1) s += __shfl_down(s, off, 64);
    __shared__ float wsum[4];
    if ((threadIdx.x & 63) == 0) wsum[threadIdx.x >> 6] = s;
    __syncthreads();
    if (threadIdx.x == 0) {
        float tot = wsum[0] + wsum[1] + wsum[2] + wsum[3];
        rs[tk] = rsqrtf(tot / (float)I_DIM + 1e-6f);
    }
}

// ===========================================================================
// Pipelined GEMM: C[M x N'] = A[M x K] . B[N' x K]^T
// BM=256, BN=128, BK=64. 8 waves (4M x 2N), per-wave 64x64 (4x4 frags).
// Triple-buffered LDS (144 KiB), depth-2 K-tile prefetch, counted vmcnt(6),
// T2 XOR swizzle (linear gld16 dest + pre-swizzled global src + swz reads).
// GATED=true : B' rows interleave gate/up at 16-granularity; epilogue gates,
//              writes bf16 hidden[M][I_DIM].
// GATED=false: epilogue scales by ds*rs[row], writes f32 out[M][H_DIM].
// ===========================================================================
template<int KDIM, bool GATED>
__global__ __launch_bounds__(512) void gemm_pipe(
    const __bf16* __restrict__ A,
    const __bf16* __restrict__ B,
    const float* __restrict__ s0,      // GATED: gate_scale ; else down_scale
    const float* __restrict__ s1,      // GATED: up_scale   ; else unused
    const float* __restrict__ rs,      // !GATED: per-row rsqrt
    void* __restrict__ outp,
    int nby)
{
    constexpr int BM = 256, BN = 128, BK = 64;
    constexpr int NT = KDIM / BK;
    constexpr int SLOTB = (BM + BN) * BK * 2;      // bytes per slot = 49152
    __shared__ __align__(16) char smem[3 * SLOTB]; // 147456 B

    // XCD-aware bijective swizzle over linear id = bx*nby + by (grid%8==0)
    const int nwg = (int)gridDim.x;
    const int q = nwg >> 3;
    const int id = (int)blockIdx.x;
    const int wg = (id & 7) * q + (id >> 3);
    const int bx = wg / nby;
    const int by = wg % nby;

    const int m0 = bx * BM;
    const int n0 = by * BN;
    const int t  = (int)threadIdx.x;
    const int lane = t & 63;
    const int wm = (t >> 6) >> 1;   // 0..3
    const int wn = (t >> 6) & 1;    // 0..1

    // ---- staging addresses (inverse-swizzled global source, linear dest) --
    const int srow = t >> 3;                                  // 0..63
    const int scol = ((t & 7) * 16) ^ ((srow & 7) << 4);      // byte col
    const char* gA = (const char*)A + (size_t)(m0 + srow) * (KDIM * 2) + scol;
    const char* gB = (const char*)B + (size_t)(n0 + srow) * (KDIM * 2) + scol;
    char* lbase = smem + t * 16;

    // ---- compute-side addresses (swizzled reads) ---------------------------
    const int l15 = lane & 15;
    const int xv  = (l15 & 7) << 4;
    const int colx[2] = { (((lane >> 4) * 16) ^ xv), ((64 + (lane >> 4) * 16) ^ xv) };

    f32x4 acc[4][4];
#pragma unroll
    for (int a = 0; a < 4; ++a)
#pragma unroll
        for (int b = 0; b < 4; ++b) acc[a][b] = (f32x4){0, 0, 0, 0};

#define STAGE_T(s, kt) do {                                                     \
        char* _ls = lbase + (s) * SLOTB;                                        \
        const char* _ga = gA + (kt) * (BK * 2);                                 \
        _Pragma("unroll")                                                       \
        for (int _i = 0; _i < 4; ++_i)                                          \
            gld16(_ls + _i * 8192, _ga + (size_t)_i * 64 * (KDIM * 2));         \
        const char* _gb = gB + (kt) * (BK * 2);                                 \
        char* _lb = _ls + BM * BK * 2;                                          \
        _Pragma("unroll")                                                       \
        for (int _i = 0; _i < 2; ++_i)                                          \
            gld16(_lb + _i * 8192, _gb + (size_t)_i * 64 * (KDIM * 2));         \
    } while (0)

#define COMPUTE_T(s) do {                                                       \
        const char* _sa = smem + (s) * SLOTB;                                   \
        const char* _sb = _sa + BM * BK * 2;                                    \
        _Pragma("unroll")                                                       \
        for (int _kk = 0; _kk < 2; ++_kk) {                                     \
            bf16x8 _a[4], _b[4];                                                \
            _Pragma("unroll")                                                   \
            for (int _f = 0; _f < 4; ++_f)                                      \
                _a[_f] = *(const bf16x8*)(_sa + (wm * 64 + _f * 16 + l15) * 128 + colx[_kk]); \
            _Pragma("unroll")                                                   \
            for (int _f = 0; _f < 4; ++_f)                                      \
                _b[_f] = *(const bf16x8*)(_sb + (wn * 64 + _f * 16 + l15) * 128 + colx[_kk]); \
            __builtin_amdgcn_s_setprio(1);                                      \
            _Pragma("unroll")                                                   \
            for (int _fm = 0; _fm < 4; ++_fm)                                   \
                _Pragma("unroll")                                               \
                for (int _fn = 0; _fn < 4; ++_fn)                               \
                    acc[_fm][_fn] = __builtin_amdgcn_mfma_f32_16x16x32_bf16(    \
                        _a[_fm], _b[_fn], acc[_fm][_fn], 0, 0, 0);              \
            __builtin_amdgcn_s_setprio(0);                                      \
        }                                                                       \
    } while (0)

    // ---- prologue: stage tiles 0,1; wait tile 0 (6 of tile 1 in flight) ----
    STAGE_T(0, 0);
    STAGE_T(1, 1);
    asm volatile("s_waitcnt vmcnt(6)" ::: "memory");
    __builtin_amdgcn_s_barrier();
    asm volatile("" ::: "memory");

    // ---- main loop: compute t from slot t%3, prefetch t+2 into (t+2)%3 -----
    for (int kt = 0; kt < NT; ++kt) {
        if (kt + 2 < NT) STAGE_T((kt + 2) % 3, kt + 2);
        COMPUTE_T(kt % 3);
        if (kt + 2 < NT) {
            asm volatile("s_waitcnt vmcnt(6)" ::: "memory");   // tile t+1 ready
            __builtin_amdgcn_s_barrier();
            asm volatile("" ::: "memory");
        } else if (kt + 2 == NT) {
            asm volatile("s_waitcnt vmcnt(0)" ::: "memory");   // last tile ready
            __builtin_amdgcn_s_barrier();
            asm volatile("" ::: "memory");
        }
    }

#undef STAGE_T
#undef COMPUTE_T

    // ---- epilogue ----------------------------------------------------------
    const int r0 = m0 + wm * 64 + (lane >> 4) * 4;
    if (GATED) {
        // fn even = gate frag, fn odd = up frag for i = by*64 + wn*32 + (fn>>1)*16 + l15
        const float comb = s0[0] * s0[0] * s1[0];
        __bf16* hid = (__bf16*)outp;
        const int i0 = by * 64 + wn * 32 + l15;
#pragma unroll
        for (int fm = 0; fm < 4; ++fm)
#pragma unroll
            for (int p = 0; p < 2; ++p)
#pragma unroll
                for (int j = 0; j < 4; ++j) {
                    float g = acc[fm][2 * p][j];
                    float u = acc[fm][2 * p + 1][j];
                    float r = fmaxf(g, 0.f);
                    hid[(size_t)(r0 + fm * 16 + j) * I_DIM + (i0 + p * 16)] =
                        (__bf16)(comb * r * r * u);
                }
    } else {
        const float ds = s0[0];
        float* outf = (float*)outp;
#pragma unroll
        for (int fm = 0; fm < 4; ++fm)
#pragma unroll
            for (int j = 0; j < 4; ++j) {
                const int row = r0 + fm * 16 + j;
                const float sc = ds * rs[row];
#pragma unroll
                for (int fn = 0; fn < 4; ++fn)
                    outf[(size_t)row * H_DIM + (n0 + wn * 64 + fn * 16 + l15)] =
                        sc * acc[fm][fn][j];
            }
    }
}

// ---------------------------------------------------------------------------
extern "C" void kernel_launch(void* const* d_in, const int* in_sizes, int n_in,
                              void* d_out, int out_size, void* d_ws, size_t ws_size,
                              hipStream_t stream) {
    const float* x   = (const float*)d_in[0];
    const int*   gp  = (const int*)d_in[1];
    const float* gs  = (const float*)d_in[2];
    const int*   upk = (const int*)d_in[3];
    const float* us  = (const float*)d_in[4];
    const int*   dp  = (const int*)d_in[5];
    const float* dsc = (const float*)d_in[6];
    const float* nw  = (const float*)d_in[7];
    float* out = (float*)d_out;

    char* ws = (char*)d_ws;
    __bf16* xb     = (__bf16*)ws;  ws += (size_t)NTOK * H_DIM * 2;          // 41.9 MB
    __bf16* bgu    = (__bf16*)ws;  ws += (size_t)2 * I_DIM * H_DIM * 2;     // 70.8 MB (combined gate/up B')
    __bf16* wdb    = (__bf16*)ws;  ws += (size_t)H_DIM * I_DIM * 2;         // 35.4 MB
    __bf16* hidden = (__bf16*)ws;  ws += (size_t)NTOK * I_DIM * 2;          // 113.2 MB
    float*  rsbuf  = (float*)ws;   ws += (size_t)NTOK * 4;

    // prep
    cvt_x_kernel<<<(NTOK * H_DIM / 8 + 255) / 256, 256, 0, stream>>>(x, xb, NTOK * H_DIM / 8);
    unpack_w_kernel<<<(I_DIM * H_DIM / 8 + 255) / 256, 256, 0, stream>>>(gp, bgu, I_DIM, H_DIM, nullptr, 1);
    unpack_w_kernel<<<(I_DIM * H_DIM / 8 + 255) / 256, 256, 0, stream>>>(upk, bgu, I_DIM, H_DIM, nullptr, 2);
    unpack_w_kernel<<<(H_DIM * I_DIM / 8 + 255) / 256, 256, 0, stream>>>(dp, wdb, H_DIM, I_DIM, nw, 0);

    // gate+up fused GEMM + gating: grid = 32 x 108 = 3456 blocks (div by 8)
    gemm_pipe<H_DIM, true><<<dim3((NTOK / 256) * (2 * I_DIM / 128)), 512, 0, stream>>>(
        xb, bgu, gs, us, nullptr, hidden, 2 * I_DIM / 128);

    // RMSNorm scale
    rms_rs_kernel<<<NTOK, 256, 0, stream>>>(hidden, rsbuf);

    // down GEMM: grid = 32 x 20 = 640 blocks (div by 8)
    gemm_pipe<I_DIM, false><<<dim3((NTOK / 256) * (H_DIM / 128)), 512, 0, stream>>>(
        hidden, wdb, dsc, nullptr, rsbuf, out, H_DIM / 128);
}

// Round 4
// 855.432 us; speedup vs baseline: 1.5704x; 1.1002x over previous
//
#include <hip/hip_runtime.h>
#include <cstdint>
#include <cstddef>

#define H_DIM 2560
#define I_DIM 6912
#define NTOK  8192   // B*S = 4*2048

typedef __attribute__((ext_vector_type(8))) __bf16 bf16x8;
typedef __attribute__((ext_vector_type(4))) float  f32x4;

// ---- async global->LDS, 16B per lane -------------------------------------
__device__ inline void gld16(void* lds, const void* g) {
    __builtin_amdgcn_global_load_lds(
        (__attribute__((address_space(1))) void*)(void*)g,
        (__attribute__((address_space(3))) void*)lds, 16, 0, 0);
}

// ---- prep: f32 -> bf16 (8 elems/thread) ----------------------------------
__global__ __launch_bounds__(256) void cvt_x_kernel(const float* __restrict__ x,
                                                    __bf16* __restrict__ xb, int n8) {
    int gid = blockIdx.x * 256 + threadIdx.x;
    if (gid >= n8) return;
    const float4* p = (const float4*)(x + (size_t)gid * 8);
    float4 v0 = p[0], v1 = p[1];
    bf16x8 o;
    o[0] = (__bf16)v0.x; o[1] = (__bf16)v0.y; o[2] = (__bf16)v0.z; o[3] = (__bf16)v0.w;
    o[4] = (__bf16)v1.x; o[5] = (__bf16)v1.y; o[6] = (__bf16)v1.z; o[7] = (__bf16)v1.w;
    *(bf16x8*)(xb + (size_t)gid * 8) = o;
}

// ---- prep: unpack SIMD-interleaved 2-bit ternary -> bf16 ------------------
// mode 0: dst row = i; mode 1/2: 16-row gate/up interleave for combined B'
__global__ __launch_bounds__(256) void unpack_w_kernel(const int* __restrict__ packed,
                                                       __bf16* __restrict__ out,
                                                       int M, int K,
                                                       const float* __restrict__ norm,
                                                       int mode) {
    int gid = blockIdx.x * 256 + threadIdx.x;
    int per_row = K >> 3;
    if (gid >= M * per_row) return;
    int i  = gid / per_row;
    int k0 = (gid % per_row) * 8;
    int blk = k0 >> 7;
    int grp = (k0 >> 5) & 3;
    int j0  = k0 & 31;
    int shift = 6 - 2 * grp;
    const int* p = packed + (size_t)i * (K >> 2) + blk * 32 + j0;
    int4 v0 = *(const int4*)p;
    int4 v1 = *(const int4*)(p + 4);
    int vals[8] = {v0.x, v0.y, v0.z, v0.w, v1.x, v1.y, v1.z, v1.w};
    bf16x8 o;
#pragma unroll
    for (int b = 0; b < 8; ++b) {
        float f = (float)(((vals[b] >> shift) & 3) - 1);
        if (norm) f *= norm[k0 + b];
        o[b] = (__bf16)f;
    }
    int dst = (mode == 0) ? i : ((i >> 4) * 32 + (i & 15) + ((mode == 2) ? 16 : 0));
    *(bf16x8*)(out + (size_t)dst * K + k0) = o;
}

// ---- per-token rsqrt(mean(hidden^2)+eps) ----------------------------------
__global__ __launch_bounds__(256) void rms_rs_kernel(const __bf16* __restrict__ hidden,
                                                     float* __restrict__ rs) {
    const int tk = blockIdx.x;
    const __bf16* row = hidden + (size_t)tk * I_DIM;
    float s = 0.f;
    for (int idx = threadIdx.x; idx < I_DIM / 8; idx += 256) {
        bf16x8 v = *(const bf16x8*)&row[idx * 8];
#pragma unroll
        for (int j = 0; j < 8; ++j) { float f = (float)v[j]; s += f * f; }
    }
#pragma unroll
    for (int off = 32; off; off >>= 1) s += __shfl_down(s, off, 64);
    __shared__ float wsum[4];
    if ((threadIdx.x & 63) == 0) wsum[threadIdx.x >> 6] = s;
    __syncthreads();
    if (threadIdx.x == 0) {
        float tot = wsum[0] + wsum[1] + wsum[2] + wsum[3];
        rs[tk] = rsqrtf(tot / (float)I_DIM + 1e-6f);
    }
}

// ===========================================================================
// 8-phase 256x256 fused gate+up GEMM (T2+T3+T4+T5).
// BM=BN=256, BK=64, 512 thr = 8 waves (2M x 4N), per-wave 128x64 C.
// LDS 128KiB = 2 buf x {A-kk0,A-kk1 | B-nh0,B-nh1} 16KB quarters.
// Per K-tile 4 phases (kk-major); 1 half staged/phase; vmcnt(4) per tile.
// Stage schedule (tile kt's phases): P1->(kt+1).Akk1, P2->(kt+1).Bnh1,
//                                    P3->(kt+2).Akk0, P4->(kt+2).Bnh0.
// WAR: each target region's last read is >=1 barrier before stage issue.
// RAW: every quarter of tile kt is >=3 stage-slots old at kt's vmcnt(4).
// A layout: 128B lines (row pairs), slot' = ((row&1)<<2|s) ^ ((row>>1)&7).
// B layout: [sr][128B], slot' = (kk*4+s) ^ (sr&7).  Both <=2-way (free).
// ===========================================================================
template<int KDIM>
__global__ __launch_bounds__(512, 2) void gemm_gu8(
    const __bf16* __restrict__ A,      // [NTOK][KDIM]
    const __bf16* __restrict__ B,      // [2*I][KDIM] gate/up 16-row interleave
    const float* __restrict__ gs_p,
    const float* __restrict__ us_p,
    __bf16* __restrict__ hidden,       // [NTOK][I_DIM]
    int nby)
{
    constexpr int KB = KDIM * 2;       // row stride bytes
    constexpr int NT = KDIM / 64;
    __shared__ __align__(16) char smem[131072];

    // bijective XCD swizzle (grid % 8 == 0)
    const int nwg = (int)gridDim.x;
    const int q = nwg >> 3;
    const int id = (int)blockIdx.x;
    const int wg = (id & 7) * q + (id >> 3);
    const int bx = wg / nby, by = wg % nby;
    const int m0 = bx * 256, n0 = by * 256;

    const int t = (int)threadIdx.x;
    const int lane = t & 63;
    const int wid = t >> 6;
    const int wm = wid >> 2, wn = wid & 3;
    const int l15 = lane & 15, s8 = lane >> 4;

    // ---- staging precompute (inverse-swizzled global src, linear LDS dest)
    const int qa  = (t & 7) ^ ((t >> 3) & 7);
    const int rA2 = ((t >> 3) << 1) + (qa >> 2);
    const char* gA0 = (const char*)A + (size_t)(m0 + rA2) * KB + (qa & 3) * 16;
    const char* gA1 = (const char*)A + (size_t)(m0 + 128 + rA2) * KB + (qa & 3) * 16;
    const int sr0 = t >> 3, sr1 = 64 + (t >> 3);
    const int br0 = ((sr0 >> 5) << 6) + (sr0 & 31);
    const int br1 = ((sr1 >> 5) << 6) + (sr1 & 31);
    const char* gB0 = (const char*)B + (size_t)(n0 + br0) * KB + qa * 16;
    const char* gB1 = (const char*)B + (size_t)(n0 + br1) * KB + qa * 16;
    char* ldst = smem + t * 16;

    // ---- compute-side read offsets (swizzled)
    const int aoff = (wm * 64 + (l15 >> 1)) * 128 +
                     (((((l15 & 1) << 2) | s8) ^ ((l15 >> 1) & 7)) << 4);
    const int boff = (wn * 32 + l15) * 128;
    const int bco0 = ((s8) ^ (l15 & 7)) << 4;
    const int bco1 = ((4 | s8) ^ (l15 & 7)) << 4;

    f32x4 acc[8][4];
#pragma unroll
    for (int f = 0; f < 8; ++f)
#pragma unroll
        for (int n = 0; n < 4; ++n) acc[f][n] = (f32x4){0, 0, 0, 0};

#define STG_A(d, kt, kk) do {                                              \
        size_t _oA = (size_t)(kt) * 128 + (kk) * 64;                       \
        gld16(ldst + (d) * 65536 + (kk) * 16384,        gA0 + _oA);        \
        gld16(ldst + (d) * 65536 + (kk) * 16384 + 8192, gA1 + _oA);        \
    } while (0)
#define STG_B(d, kt, nh) do {                                              \
        size_t _oB = (size_t)(nh) * 32 * KB + (size_t)(kt) * 128;          \
        gld16(ldst + (d) * 65536 + 32768 + (nh) * 16384,        gB0 + _oB);\
        gld16(ldst + (d) * 65536 + 32768 + (nh) * 16384 + 8192, gB1 + _oB);\
    } while (0)
#define LOAD_A(d, kk) do { _Pragma("unroll")                               \
        for (int _f = 0; _f < 8; ++_f)                                     \
            a[_f] = *(const bf16x8*)(smem + (d) * 65536 + (kk) * 16384 +   \
                                     _f * 1024 + aoff); } while (0)
#define LOAD_B(d, nh, bc) do {                                             \
        b0 = *(const bf16x8*)(smem + (d) * 65536 + 32768 + (nh) * 16384 +  \
                              boff + (bc));                                \
        b1 = *(const bf16x8*)(smem + (d) * 65536 + 32768 + (nh) * 16384 +  \
                              boff + (bc) + 2048); } while (0)
#define MFMA16(nh) do { __builtin_amdgcn_s_setprio(1); _Pragma("unroll")   \
        for (int _f = 0; _f < 8; ++_f) {                                   \
            acc[_f][(nh) * 2] = __builtin_amdgcn_mfma_f32_16x16x32_bf16(   \
                a[_f], b0, acc[_f][(nh) * 2], 0, 0, 0);                    \
            acc[_f][(nh) * 2 + 1] = __builtin_amdgcn_mfma_f32_16x16x32_bf16(\
                a[_f], b1, acc[_f][(nh) * 2 + 1], 0, 0, 0); }              \
        __builtin_amdgcn_s_setprio(0); } while (0)
#define BAR() do { asm volatile("" ::: "memory");                          \
        __builtin_amdgcn_s_barrier();                                      \
        asm volatile("" ::: "memory"); } while (0)

    // ---- prologue: tile0 full + tile1 {Akk0, Bnh0}; tile0 guaranteed ------
    STG_A(0, 0, 0); STG_A(0, 0, 1); STG_B(0, 0, 0); STG_B(0, 0, 1);
    STG_A(1, 1, 0); STG_B(1, 1, 0);
    asm volatile("s_waitcnt vmcnt(4)" ::: "memory");
    BAR();

    bf16x8 a[8], b0, b1;
    for (int kt = 0; kt < NT; ++kt) {
        const int d = kt & 1;
        // P1: (kk0, nh0)
        LOAD_A(d, 0); LOAD_B(d, 0, bco0);
        if (kt + 1 < NT) STG_A(d ^ 1, kt + 1, 1);
        BAR(); MFMA16(0); BAR();
        // P2: (kk0, nh1)
        LOAD_B(d, 1, bco0);
        if (kt + 1 < NT) STG_B(d ^ 1, kt + 1, 1);
        BAR(); MFMA16(1); BAR();
        // P3: (kk1, nh0)
        LOAD_A(d, 1); LOAD_B(d, 0, bco1);
        if (kt + 2 < NT) STG_A(d, kt + 2, 0);
        BAR(); MFMA16(0); BAR();
        // P4: (kk1, nh1) + tile-boundary counted vmcnt
        LOAD_B(d, 1, bco1);
        if (kt + 2 < NT) {
            STG_B(d, kt + 2, 0);
            asm volatile("s_waitcnt vmcnt(4)" ::: "memory");
        } else {
            asm volatile("s_waitcnt vmcnt(0)" ::: "memory");
        }
        BAR(); MFMA16(1); BAR();
    }

#undef STG_A
#undef STG_B
#undef LOAD_A
#undef LOAD_B
#undef MFMA16
#undef BAR

    // ---- epilogue: hidden = gs^2*us * relu(g)^2 * u ------------------------
    const float comb = gs_p[0] * gs_p[0] * us_p[0];
    const int r0 = m0 + wm * 128 + s8 * 4;
#pragma unroll
    for (int f = 0; f < 8; ++f)
#pragma unroll
        for (int p = 0; p < 2; ++p)
#pragma unroll
            for (int j = 0; j < 4; ++j) {
                float g = acc[f][2 * p][j];
                float u = acc[f][2 * p + 1][j];
                float r = fmaxf(g, 0.f);
                hidden[(size_t)(r0 + f * 16 + j) * I_DIM +
                       ((by * 8 + wn * 2 + p) * 16 + l15)] = (__bf16)(comb * r * r * u);
            }
}

// ===========================================================================
// Down GEMM (proven R3 structure): BM=256, BN=128, BK=64, triple-buffer,
// depth-2 prefetch, vmcnt(6), T2 swizzle, T5 setprio.
// ===========================================================================
template<int KDIM>
__global__ __launch_bounds__(512) void gemm_down_pipe(
    const __bf16* __restrict__ A,      // hidden [NTOK][KDIM]
    const __bf16* __restrict__ B,      // Wd [H][KDIM] (norm_w folded)
    const float* __restrict__ ds_p,
    const float* __restrict__ rs,
    float* __restrict__ outf,
    int nby)
{
    constexpr int BM = 256, BN = 128, BK = 64;
    constexpr int NT = KDIM / BK;
    constexpr int SLOTB = (BM + BN) * BK * 2;
    __shared__ __align__(16) char smem[3 * SLOTB];

    const int nwg = (int)gridDim.x;
    const int q = nwg >> 3;
    const int id = (int)blockIdx.x;
    const int wg = (id & 7) * q + (id >> 3);
    const int bx = wg / nby;
    const int by = wg % nby;

    const int m0 = bx * BM;
    const int n0 = by * BN;
    const int t  = (int)threadIdx.x;
    const int lane = t & 63;
    const int wm = (t >> 6) >> 1;
    const int wn = (t >> 6) & 1;

    const int srow = t >> 3;
    const int scol = ((t & 7) * 16) ^ ((srow & 7) << 4);
    const char* gA = (const char*)A + (size_t)(m0 + srow) * (KDIM * 2) + scol;
    const char* gB = (const char*)B + (size_t)(n0 + srow) * (KDIM * 2) + scol;
    char* lbase = smem + t * 16;

    const int l15 = lane & 15;
    const int xv  = (l15 & 7) << 4;
    const int colx[2] = { (((lane >> 4) * 16) ^ xv), ((64 + (lane >> 4) * 16) ^ xv) };

    f32x4 acc[4][4];
#pragma unroll
    for (int a = 0; a < 4; ++a)
#pragma unroll
        for (int b = 0; b < 4; ++b) acc[a][b] = (f32x4){0, 0, 0, 0};

#define STAGE_T(s, kt) do {                                                     \
        char* _ls = lbase + (s) * SLOTB;                                        \
        const char* _ga = gA + (kt) * (BK * 2);                                 \
        _Pragma("unroll")                                                       \
        for (int _i = 0; _i < 4; ++_i)                                          \
            gld16(_ls + _i * 8192, _ga + (size_t)_i * 64 * (KDIM * 2));         \
        const char* _gb = gB + (kt) * (BK * 2);                                 \
        char* _lb = _ls + BM * BK * 2;                                          \
        _Pragma("unroll")                                                       \
        for (int _i = 0; _i < 2; ++_i)                                          \
            gld16(_lb + _i * 8192, _gb + (size_t)_i * 64 * (KDIM * 2));         \
    } while (0)

#define COMPUTE_T(s) do {                                                       \
        const char* _sa = smem + (s) * SLOTB;                                   \
        const char* _sb = _sa + BM * BK * 2;                                    \
        _Pragma("unroll")                                                       \
        for (int _kk = 0; _kk < 2; ++_kk) {                                     \
            bf16x8 _a[4], _b[4];                                                \
            _Pragma("unroll")                                                   \
            for (int _f = 0; _f < 4; ++_f)                                      \
                _a[_f] = *(const bf16x8*)(_sa + (wm * 64 + _f * 16 + l15) * 128 + colx[_kk]); \
            _Pragma("unroll")                                                   \
            for (int _f = 0; _f < 4; ++_f)                                      \
                _b[_f] = *(const bf16x8*)(_sb + (wn * 64 + _f * 16 + l15) * 128 + colx[_kk]); \
            __builtin_amdgcn_s_setprio(1);                                      \
            _Pragma("unroll")                                                   \
            for (int _fm = 0; _fm < 4; ++_fm)                                   \
                _Pragma("unroll")                                               \
                for (int _fn = 0; _fn < 4; ++_fn)                               \
                    acc[_fm][_fn] = __builtin_amdgcn_mfma_f32_16x16x32_bf16(    \
                        _a[_fm], _b[_fn], acc[_fm][_fn], 0, 0, 0);              \
            __builtin_amdgcn_s_setprio(0);                                      \
        }                                                                       \
    } while (0)

    STAGE_T(0, 0);
    STAGE_T(1, 1);
    asm volatile("s_waitcnt vmcnt(6)" ::: "memory");
    __builtin_amdgcn_s_barrier();
    asm volatile("" ::: "memory");

    for (int kt = 0; kt < NT; ++kt) {
        if (kt + 2 < NT) STAGE_T((kt + 2) % 3, kt + 2);
        COMPUTE_T(kt % 3);
        if (kt + 2 < NT) {
            asm volatile("s_waitcnt vmcnt(6)" ::: "memory");
            __builtin_amdgcn_s_barrier();
            asm volatile("" ::: "memory");
        } else if (kt + 2 == NT) {
            asm volatile("s_waitcnt vmcnt(0)" ::: "memory");
            __builtin_amdgcn_s_barrier();
            asm volatile("" ::: "memory");
        }
    }

#undef STAGE_T
#undef COMPUTE_T

    const float ds = ds_p[0];
    const int r0 = m0 + wm * 64 + (lane >> 4) * 4;
#pragma unroll
    for (int fm = 0; fm < 4; ++fm)
#pragma unroll
        for (int j = 0; j < 4; ++j) {
            const int row = r0 + fm * 16 + j;
            const float sc = ds * rs[row];
#pragma unroll
            for (int fn = 0; fn < 4; ++fn)
                outf[(size_t)row * H_DIM + (n0 + wn * 64 + fn * 16 + l15)] =
                    sc * acc[fm][fn][j];
        }
}

// ---------------------------------------------------------------------------
extern "C" void kernel_launch(void* const* d_in, const int* in_sizes, int n_in,
                              void* d_out, int out_size, void* d_ws, size_t ws_size,
                              hipStream_t stream) {
    const float* x   = (const float*)d_in[0];
    const int*   gp  = (const int*)d_in[1];
    const float* gs  = (const float*)d_in[2];
    const int*   upk = (const int*)d_in[3];
    const float* us  = (const float*)d_in[4];
    const int*   dp  = (const int*)d_in[5];
    const float* dsc = (const float*)d_in[6];
    const float* nw  = (const float*)d_in[7];
    float* out = (float*)d_out;

    char* ws = (char*)d_ws;
    __bf16* xb     = (__bf16*)ws;  ws += (size_t)NTOK * H_DIM * 2;
    __bf16* bgu    = (__bf16*)ws;  ws += (size_t)2 * I_DIM * H_DIM * 2;
    __bf16* wdb    = (__bf16*)ws;  ws += (size_t)H_DIM * I_DIM * 2;
    __bf16* hidden = (__bf16*)ws;  ws += (size_t)NTOK * I_DIM * 2;
    float*  rsbuf  = (float*)ws;   ws += (size_t)NTOK * 4;

    // prep
    cvt_x_kernel<<<(NTOK * H_DIM / 8 + 255) / 256, 256, 0, stream>>>(x, xb, NTOK * H_DIM / 8);
    unpack_w_kernel<<<(I_DIM * H_DIM / 8 + 255) / 256, 256, 0, stream>>>(gp, bgu, I_DIM, H_DIM, nullptr, 1);
    unpack_w_kernel<<<(I_DIM * H_DIM / 8 + 255) / 256, 256, 0, stream>>>(upk, bgu, I_DIM, H_DIM, nullptr, 2);
    unpack_w_kernel<<<(H_DIM * I_DIM / 8 + 255) / 256, 256, 0, stream>>>(dp, wdb, H_DIM, I_DIM, nw, 0);

    // gate+up fused 8-phase GEMM: grid = 32 x 54 = 1728 blocks (div by 8)
    gemm_gu8<H_DIM><<<dim3((NTOK / 256) * (2 * I_DIM / 256)), 512, 0, stream>>>(
        xb, bgu, gs, us, hidden, 2 * I_DIM / 256);

    // RMSNorm scale
    rms_rs_kernel<<<NTOK, 256, 0, stream>>>(hidden, rsbuf);

    // down GEMM: grid = 32 x 20 = 640 blocks (div by 8)
    gemm_down_pipe<I_DIM><<<dim3((NTOK / 256) * (H_DIM / 128)), 512, 0, stream>>>(
        hidden, wdb, dsc, rsbuf, out, H_DIM / 128);
}